// Round 5
// baseline (490.094 us; speedup 1.0000x reference)
//
#include <hip/hip_runtime.h>
#include <hip/hip_bf16.h>

typedef unsigned short ushort_t;
typedef __attribute__((ext_vector_type(8))) short short8;
typedef __attribute__((ext_vector_type(8))) __bf16 bf16x8;
typedef __attribute__((ext_vector_type(4))) float f32x4;

#define LQS 4096
#define LKS 4096
#define NH 16
#define HD 64
#define DIN 1024
#define QBLK 128
#define KVB 64
static constexpr float TAU_S = 0.125f;  // 1/sqrt(64)
static constexpr float LOG2E = 1.4426950408889634f;

__device__ __forceinline__ float exp2_fast(float x) { return __builtin_amdgcn_exp2f(x); }

__device__ __forceinline__ ushort_t f32_to_bf16(float x) {
  union { float f; unsigned u; } v; v.f = x;
  unsigned r = v.u + 0x7FFF + ((v.u >> 16) & 1);
  return (ushort_t)(r >> 16);
}

__device__ __forceinline__ void gld_lds16(const void* g, void* l) {
  __builtin_amdgcn_global_load_lds((const __attribute__((address_space(1))) void*)g,
                                   (__attribute__((address_space(3))) void*)l, 16, 0, 0);
}

__device__ __forceinline__ f32x4 mfma16(bf16x8 a, bf16x8 b, f32x4 c) {
  return __builtin_amdgcn_mfma_f32_16x16x32_bf16(a, b, c, 0, 0, 0);
}

// ---------------- batched convert f32 -> bf16 (8 elems/thread) ----------------
struct Cvt3 { const float* src[3]; ushort_t* dst[3]; };
__global__ void cvt_kernel(Cvt3 c) {
  const float* __restrict__ src = c.src[blockIdx.y];
  ushort_t* __restrict__ dst = c.dst[blockIdx.y];
  int i = (blockIdx.x * 256 + threadIdx.x) * 8;
  float4 a = *(const float4*)(src + i);
  float4 b = *(const float4*)(src + i + 4);
  short8 o;
  o[0] = (short)f32_to_bf16(a.x); o[1] = (short)f32_to_bf16(a.y);
  o[2] = (short)f32_to_bf16(a.z); o[3] = (short)f32_to_bf16(a.w);
  o[4] = (short)f32_to_bf16(b.x); o[5] = (short)f32_to_bf16(b.y);
  o[6] = (short)f32_to_bf16(b.z); o[7] = (short)f32_to_bf16(b.w);
  *(short8*)(dst + i) = o;
}

// ---------------- batched transpose + convert W [1024][1024] f32 -> bf16 ----------------
struct TW4 { const float* W[4]; ushort_t* Wt[4]; };
__global__ void transpose_w(TW4 w) {
  const float* __restrict__ W = w.W[blockIdx.z];
  ushort_t* __restrict__ Wt = w.Wt[blockIdx.z];
  __shared__ float tile[64][65];
  const int t = threadIdx.x;
  const int k0 = blockIdx.y * 64, n0 = blockIdx.x * 64;
#pragma unroll
  for (int i = 0; i < 16; ++i) {
    int idx = i * 256 + t;
    int r = idx >> 6, c = idx & 63;
    tile[r][c] = W[(size_t)(k0 + r) * DIN + n0 + c];
  }
  __syncthreads();
#pragma unroll
  for (int i = 0; i < 16; ++i) {
    int idx = i * 256 + t;
    int r = idx >> 6, c = idx & 63;  // r: n-local, c: k-local
    Wt[(size_t)(n0 + r) * DIN + k0 + c] = f32_to_bf16(tile[c][r]);
  }
}

// ---------------- transpose vh [4096][16*64] -> vt [16][64][4096] ----------------
__global__ void transpose_v(const ushort_t* __restrict__ vh, ushort_t* __restrict__ vt) {
  __shared__ ushort_t tile[64][65];
  const int t = threadIdx.x;
  const int k0 = blockIdx.x * 64, h = blockIdx.y;
#pragma unroll
  for (int i = 0; i < 16; ++i) {
    int idx = i * 256 + t;
    int r = idx >> 6, c = idx & 63;  // r: k-local, c: x
    tile[r][c] = vh[(size_t)(k0 + r) * DIN + h * HD + c];
  }
  __syncthreads();
#pragma unroll
  for (int i = 0; i < 16; ++i) {
    int idx = i * 256 + t;
    int r = idx >> 6, c = idx & 63;  // r: x, c: k-local
    vt[((size_t)h * HD + r) * (size_t)LKS + k0 + c] = tile[c][r];
  }
}

// ---------------- NT GEMM (R1-proven 128x128 config, batched) ----------------
// M=4096, N=1024, K=1024 for all uses. 4 waves (2x2), per-wave 64x64, BK=64.
struct Batch3 {
  const ushort_t* A[3];
  const ushort_t* Bt[3];
  const float* bias[3];
  void* C[3];
  float scale[3];
};
template <bool OUT_F32>
__launch_bounds__(256, 2)
__global__ void gemm_nt(Batch3 bt3) {
  const int z = blockIdx.z;
  const ushort_t* __restrict__ A = bt3.A[z];
  const ushort_t* __restrict__ Bt = bt3.Bt[z];
  const float* __restrict__ bias = bt3.bias[z];
  void* __restrict__ Cout = bt3.C[z];
  const float scale = bt3.scale[z];
  const int K = DIN, N = DIN;

  __shared__ __align__(16) ushort_t Alds[128 * 64];
  __shared__ __align__(16) ushort_t Blds[128 * 64];
  const int t = threadIdx.x, wave = t >> 6, lane = t & 63;
  const int l15 = lane & 15, lg = lane >> 4;
  const int m0 = blockIdx.y * 128, n0 = blockIdx.x * 128;
  const int wr = wave >> 1, wc = wave & 1;
  f32x4 acc[4][4];
#pragma unroll
  for (int i = 0; i < 4; ++i)
#pragma unroll
    for (int j = 0; j < 4; ++j) acc[i][j] = (f32x4){0.f, 0.f, 0.f, 0.f};

  for (int tk = 0; tk < K / 64; ++tk) {
#pragma unroll
    for (int c = 0; c < 4; ++c) {
      int chunk = wave * 4 + c;
      int row = chunk * 8 + (lane >> 3);
      int ss = (lane & 7) ^ (row & 7);
      gld_lds16(A + (size_t)(m0 + row) * K + tk * 64 + ss * 8, (char*)Alds + chunk * 1024);
      gld_lds16(Bt + (size_t)(n0 + row) * K + tk * 64 + ss * 8, (char*)Blds + chunk * 1024);
    }
    __syncthreads();
#pragma unroll
    for (int kk = 0; kk < 2; ++kk) {
      bf16x8 a[4], b[4];
#pragma unroll
      for (int i = 0; i < 4; ++i) {
        int ra = wr * 64 + i * 16 + l15;
        a[i] = *(const bf16x8*)((const char*)Alds + ra * 128 + ((((kk * 4 + lg) << 4)) ^ ((ra & 7) << 4)));
        int rb = wc * 64 + i * 16 + l15;
        b[i] = *(const bf16x8*)((const char*)Blds + rb * 128 + ((((kk * 4 + lg) << 4)) ^ ((rb & 7) << 4)));
      }
#pragma unroll
      for (int mi = 0; mi < 4; ++mi)
#pragma unroll
        for (int ni = 0; ni < 4; ++ni)
          acc[mi][ni] = mfma16(a[mi], b[ni], acc[mi][ni]);
    }
    __syncthreads();
  }
#pragma unroll
  for (int ni = 0; ni < 4; ++ni) {
    int coln = n0 + wc * 64 + ni * 16 + l15;
    float bv = bias[coln];
#pragma unroll
    for (int mi = 0; mi < 4; ++mi) {
#pragma unroll
      for (int r = 0; r < 4; ++r) {
        int rowm = m0 + wr * 64 + mi * 16 + lg * 4 + r;
        float v = (acc[mi][ni][r] + bv) * scale;
        if (OUT_F32)
          ((float*)Cout)[(size_t)rowm * N + coln] = v;
        else
          ((ushort_t*)Cout)[(size_t)rowm * N + coln] = f32_to_bf16(v);
      }
    }
  }
}

// ---------------- fused attention, 2-phase double-buffered ----------------
// grid: (LQ/128, NH), block 512 (8 waves), wave w owns Q rows [q0+16w, q0+16w+16).
// qh pre-scaled by TAU*log2(e) -> softmax via exp2.
// KVB=64 tiles; K/V double-buffered; stage issued BEFORE compute; 1 barrier/tile.
__launch_bounds__(512, 4)
__global__ void attn_kernel(const ushort_t* __restrict__ qh, const ushort_t* __restrict__ kh,
                            const ushort_t* __restrict__ vt, float* __restrict__ att,
                            ushort_t* __restrict__ ctx) {
  __shared__ __align__(16) ushort_t Klds[2][KVB * 64];   // [k-row][d] 128B rows, 8KB each
  __shared__ __align__(16) ushort_t Vlds[2][KVB * 64];   // [x][k]    128B rows, 8KB each
  __shared__ __align__(16) ushort_t Plds[8][16 * KVB];   // per-wave [q][k], 128B rows, 2KB each
  const int t = threadIdx.x, wave = t >> 6, lane = t & 63;
  const int l15 = lane & 15, lg = lane >> 4;
  const int h = blockIdx.y;
  const int q0 = blockIdx.x * QBLK;

  // staging geometry: 64 rows x 128B; thread t -> row t>>3, 16B slot (t&7)^(row&7).
  const int srow = t >> 3;
  const int sslot = (t & 7) ^ (srow & 7);
  const ushort_t* kbase = kh + (size_t)srow * DIN + h * HD + sslot * 8;
  const ushort_t* vbase = vt + ((size_t)h * HD + srow) * (size_t)LKS + sslot * 8;

  bf16x8 qa[2];
  {
    int row = q0 + wave * 16 + l15;
    const ushort_t* qp = qh + (size_t)row * DIN + h * HD + lg * 8;
    qa[0] = *(const bf16x8*)(qp);
    qa[1] = *(const bf16x8*)(qp + 32);
  }

  float rs[4] = {0.f, 0.f, 0.f, 0.f};
  // ---- pass 1: row sums (K only, dbuf) ----
  gld_lds16(kbase, (char*)Klds[0] + wave * 1024);
  __syncthreads();
  int cur = 0;
  for (int tk = 0; tk < LKS / KVB; ++tk) {
    if (tk + 1 < LKS / KVB)
      gld_lds16(kbase + (size_t)(tk + 1) * KVB * DIN, (char*)Klds[cur ^ 1] + wave * 1024);
#pragma unroll
    for (int ct = 0; ct < 4; ++ct) {
      f32x4 acc = (f32x4){0.f, 0.f, 0.f, 0.f};
#pragma unroll
      for (int kk = 0; kk < 2; ++kk) {
        int row = ct * 16 + l15;
        bf16x8 kb = *(const bf16x8*)((const char*)Klds[cur] + row * 128 + ((((kk * 4 + lg) << 4)) ^ ((row & 7) << 4)));
        acc = mfma16(qa[kk], kb, acc);
      }
#pragma unroll
      for (int r = 0; r < 4; ++r) rs[r] += exp2_fast(acc[r]);
    }
    __syncthreads();
    cur ^= 1;
  }
#pragma unroll
  for (int m = 1; m < 16; m <<= 1) {
#pragma unroll
    for (int r = 0; r < 4; ++r) rs[r] += __shfl_xor(rs[r], m, 64);
  }
  float recip[4];
#pragma unroll
  for (int r = 0; r < 4; ++r) recip[r] = 1.0f / rs[r];

  // ---- pass 2: att write + PV (K+V dbuf) ----
  f32x4 cacc[4];
#pragma unroll
  for (int x = 0; x < 4; ++x) cacc[x] = (f32x4){0.f, 0.f, 0.f, 0.f};
  float* atth = att + ((size_t)h << 24);

  gld_lds16(kbase, (char*)Klds[0] + wave * 1024);
  gld_lds16(vbase, (char*)Vlds[0] + wave * 1024);
  __syncthreads();
  cur = 0;
  for (int tk = 0; tk < LKS / KVB; ++tk) {
    if (tk + 1 < LKS / KVB) {
      gld_lds16(kbase + (size_t)(tk + 1) * KVB * DIN, (char*)Klds[cur ^ 1] + wave * 1024);
      gld_lds16(vbase + (tk + 1) * KVB, (char*)Vlds[cur ^ 1] + wave * 1024);
    }
#pragma unroll
    for (int ct = 0; ct < 4; ++ct) {
      f32x4 acc = (f32x4){0.f, 0.f, 0.f, 0.f};
#pragma unroll
      for (int kk = 0; kk < 2; ++kk) {
        int row = ct * 16 + l15;
        bf16x8 kb = *(const bf16x8*)((const char*)Klds[cur] + row * 128 + ((((kk * 4 + lg) << 4)) ^ ((row & 7) << 4)));
        acc = mfma16(qa[kk], kb, acc);
      }
#pragma unroll
      for (int r = 0; r < 4; ++r) {
        float p = exp2_fast(acc[r]) * recip[r];
        int rowq = q0 + wave * 16 + lg * 4 + r;
        int col = tk * KVB + ct * 16 + l15;
        atth[((size_t)rowq << 12) + col] = p;
        int R = lg * 4 + r;  // row within wave's private P tile
        int byte = R * 128 + ((ct * 32 + l15 * 2) ^ ((R & 7) << 4));
        *(ushort_t*)((char*)Plds[wave] + byte) = f32_to_bf16(p);
      }
    }
    // PV: ctx[q][x] += sum_k P[q][k] * V[k][x]   (P wave-private; lgkmcnt auto)
    bf16x8 pa[2];
#pragma unroll
    for (int kk = 0; kk < 2; ++kk) {
      int R = l15;
      pa[kk] = *(const bf16x8*)((const char*)Plds[wave] + R * 128 + ((((kk * 4 + lg) << 4)) ^ ((R & 7) << 4)));
    }
#pragma unroll
    for (int x = 0; x < 4; ++x) {
#pragma unroll
      for (int kk = 0; kk < 2; ++kk) {
        int rv = x * 16 + l15;
        bf16x8 vb = *(const bf16x8*)((const char*)Vlds[cur] + rv * 128 + ((((kk * 4 + lg) << 4)) ^ ((rv & 7) << 4)));
        cacc[x] = mfma16(pa[kk], vb, cacc[x]);
      }
    }
    __syncthreads();
    cur ^= 1;
  }
#pragma unroll
  for (int x = 0; x < 4; ++x) {
#pragma unroll
    for (int r = 0; r < 4; ++r) {
      int rowq = q0 + wave * 16 + lg * 4 + r;
      int col = h * HD + x * 16 + l15;
      ctx[(size_t)rowq * DIN + col] = f32_to_bf16(cacc[x][r]);
    }
  }
}

extern "C" void kernel_launch(void* const* d_in, const int* in_sizes, int n_in,
                              void* d_out, int out_size, void* d_ws, size_t ws_size,
                              hipStream_t stream) {
  const float* q = (const float*)d_in[0];
  const float* k = (const float*)d_in[1];
  const float* v = (const float*)d_in[2];
  const float* Wq = (const float*)d_in[3];
  const float* bq = (const float*)d_in[4];
  const float* Wk = (const float*)d_in[5];
  const float* bk = (const float*)d_in[6];
  const float* Wv = (const float*)d_in[7];
  const float* bv = (const float*)d_in[8];
  const float* Wo = (const float*)d_in[9];
  const float* bo = (const float*)d_in[10];

  float* out = (float*)d_out;
  float* att = out + (size_t)LQS * DIN;

  char* ws = (char*)d_ws;
  ushort_t* qhb = (ushort_t*)(ws + (size_t)0);
  ushort_t* khb = (ushort_t*)(ws + ((size_t)8 << 20));
  ushort_t* vhb = (ushort_t*)(ws + ((size_t)16 << 20));
  ushort_t* vtb = (ushort_t*)(ws + ((size_t)24 << 20));
  ushort_t* ctx = (ushort_t*)(ws + ((size_t)32 << 20));
  ushort_t* qb = (ushort_t*)(ws + ((size_t)40 << 20));
  ushort_t* kb = (ushort_t*)(ws + ((size_t)48 << 20));
  ushort_t* vb = (ushort_t*)(ws + ((size_t)56 << 20));
  ushort_t* Wqt = (ushort_t*)(ws + ((size_t)64 << 20));
  ushort_t* Wkt = (ushort_t*)(ws + ((size_t)66 << 20));
  ushort_t* Wvt = (ushort_t*)(ws + ((size_t)68 << 20));
  ushort_t* Wot = (ushort_t*)(ws + ((size_t)70 << 20));

  Cvt3 c3;
  c3.src[0] = q; c3.src[1] = k; c3.src[2] = v;
  c3.dst[0] = qb; c3.dst[1] = kb; c3.dst[2] = vb;
  cvt_kernel<<<dim3(LQS * DIN / 8 / 256, 3), 256, 0, stream>>>(c3);

  TW4 w4;
  w4.W[0] = Wq; w4.W[1] = Wk; w4.W[2] = Wv; w4.W[3] = Wo;
  w4.Wt[0] = Wqt; w4.Wt[1] = Wkt; w4.Wt[2] = Wvt; w4.Wt[3] = Wot;
  transpose_w<<<dim3(16, 16, 4), 256, 0, stream>>>(w4);

  Batch3 pb;
  pb.A[0] = qb; pb.A[1] = kb; pb.A[2] = vb;
  pb.Bt[0] = Wqt; pb.Bt[1] = Wkt; pb.Bt[2] = Wvt;
  pb.bias[0] = bq; pb.bias[1] = bk; pb.bias[2] = bv;
  pb.C[0] = qhb; pb.C[1] = khb; pb.C[2] = vhb;
  pb.scale[0] = TAU_S * LOG2E; pb.scale[1] = 1.0f; pb.scale[2] = 1.0f;
  gemm_nt<false><<<dim3(DIN / 128, LQS / 128, 3), 256, 0, stream>>>(pb);

  transpose_v<<<dim3(64, 16), 256, 0, stream>>>(vhb, vtb);

  attn_kernel<<<dim3(LQS / QBLK, NH), 512, 0, stream>>>(qhb, khb, vtb, att, ctx);

  Batch3 ob;
  ob.A[0] = ctx; ob.A[1] = ctx; ob.A[2] = ctx;
  ob.Bt[0] = Wot; ob.Bt[1] = Wot; ob.Bt[2] = Wot;
  ob.bias[0] = bo; ob.bias[1] = bo; ob.bias[2] = bo;
  ob.C[0] = out; ob.C[1] = out; ob.C[2] = out;
  ob.scale[0] = 1.0f; ob.scale[1] = 1.0f; ob.scale[2] = 1.0f;
  gemm_nt<true><<<dim3(DIN / 128, LQS / 128, 1), 256, 0, stream>>>(ob);
}

// Round 6
// 451.888 us; speedup vs baseline: 1.0845x; 1.0845x over previous
//
#include <hip/hip_runtime.h>
#include <hip/hip_bf16.h>

typedef unsigned short ushort_t;
typedef __attribute__((ext_vector_type(8))) short short8;
typedef __attribute__((ext_vector_type(8))) __bf16 bf16x8;
typedef __attribute__((ext_vector_type(4))) float f32x4;

#define LQS 4096
#define LKS 4096
#define NH 16
#define HD 64
#define DIN 1024
#define QBLK 64
#define KVB 64
static constexpr float TAU_S = 0.125f;  // 1/sqrt(64)
static constexpr float LOG2E = 1.4426950408889634f;

__device__ __forceinline__ float exp2_fast(float x) { return __builtin_amdgcn_exp2f(x); }

__device__ __forceinline__ ushort_t f32_to_bf16(float x) {
  union { float f; unsigned u; } v; v.f = x;
  unsigned r = v.u + 0x7FFF + ((v.u >> 16) & 1);
  return (ushort_t)(r >> 16);
}

__device__ __forceinline__ void gld_lds16(const void* g, void* l) {
  __builtin_amdgcn_global_load_lds((const __attribute__((address_space(1))) void*)g,
                                   (__attribute__((address_space(3))) void*)l, 16, 0, 0);
}

__device__ __forceinline__ f32x4 mfma16(bf16x8 a, bf16x8 b, f32x4 c) {
  return __builtin_amdgcn_mfma_f32_16x16x32_bf16(a, b, c, 0, 0, 0);
}

// ---------------- batched convert f32 -> bf16 (8 elems/thread) ----------------
struct Cvt3 { const float* src[3]; ushort_t* dst[3]; };
__global__ void cvt_kernel(Cvt3 c) {
  const float* __restrict__ src = c.src[blockIdx.y];
  ushort_t* __restrict__ dst = c.dst[blockIdx.y];
  int i = (blockIdx.x * 256 + threadIdx.x) * 8;
  float4 a = *(const float4*)(src + i);
  float4 b = *(const float4*)(src + i + 4);
  short8 o;
  o[0] = (short)f32_to_bf16(a.x); o[1] = (short)f32_to_bf16(a.y);
  o[2] = (short)f32_to_bf16(a.z); o[3] = (short)f32_to_bf16(a.w);
  o[4] = (short)f32_to_bf16(b.x); o[5] = (short)f32_to_bf16(b.y);
  o[6] = (short)f32_to_bf16(b.z); o[7] = (short)f32_to_bf16(b.w);
  *(short8*)(dst + i) = o;
}

// ---------------- batched transpose + convert W [1024][1024] f32 -> bf16 ----------------
struct TW4 { const float* W[4]; ushort_t* Wt[4]; };
__global__ void transpose_w(TW4 w) {
  const float* __restrict__ W = w.W[blockIdx.z];
  ushort_t* __restrict__ Wt = w.Wt[blockIdx.z];
  __shared__ float tile[64][65];
  const int t = threadIdx.x;
  const int k0 = blockIdx.y * 64, n0 = blockIdx.x * 64;
#pragma unroll
  for (int i = 0; i < 16; ++i) {
    int idx = i * 256 + t;
    int r = idx >> 6, c = idx & 63;
    tile[r][c] = W[(size_t)(k0 + r) * DIN + n0 + c];
  }
  __syncthreads();
#pragma unroll
  for (int i = 0; i < 16; ++i) {
    int idx = i * 256 + t;
    int r = idx >> 6, c = idx & 63;  // r: n-local, c: k-local
    Wt[(size_t)(n0 + r) * DIN + k0 + c] = f32_to_bf16(tile[c][r]);
  }
}

// ---------------- transpose vh [4096][16*64] -> vt [16][64][4096] ----------------
__global__ void transpose_v(const ushort_t* __restrict__ vh, ushort_t* __restrict__ vt) {
  __shared__ ushort_t tile[64][65];
  const int t = threadIdx.x;
  const int k0 = blockIdx.x * 64, h = blockIdx.y;
#pragma unroll
  for (int i = 0; i < 16; ++i) {
    int idx = i * 256 + t;
    int r = idx >> 6, c = idx & 63;  // r: k-local, c: x
    tile[r][c] = vh[(size_t)(k0 + r) * DIN + h * HD + c];
  }
  __syncthreads();
#pragma unroll
  for (int i = 0; i < 16; ++i) {
    int idx = i * 256 + t;
    int r = idx >> 6, c = idx & 63;  // r: x, c: k-local
    vt[((size_t)h * HD + r) * (size_t)LKS + k0 + c] = tile[c][r];
  }
}

// ---------------- NT GEMM (128x128, BK=64, 4 waves 2x2), XCD-swizzled 1D grid --------
// grid = 256*NZ blocks: xcd=bid&7, idx=bid>>3, z=idx>>5, rem=idx&31, by=xcd*4+(rem>>3), bx=rem&7
struct Batch3 {
  const ushort_t* A[3];
  const ushort_t* Bt[3];
  const float* bias[3];
  void* C[3];
  float scale[3];
};
template <bool OUT_F32>
__launch_bounds__(256, 2)
__global__ void gemm_nt(Batch3 bt3) {
  const int bid = blockIdx.x;
  const int xcd = bid & 7, idx = bid >> 3;
  const int z = idx >> 5, rem = idx & 31;
  const int by = xcd * 4 + (rem >> 3), bx = rem & 7;
  const ushort_t* __restrict__ A = bt3.A[z];
  const ushort_t* __restrict__ Bt = bt3.Bt[z];
  const float* __restrict__ bias = bt3.bias[z];
  void* __restrict__ Cout = bt3.C[z];
  const float scale = bt3.scale[z];
  const int K = DIN, N = DIN;

  __shared__ __align__(16) ushort_t Alds[128 * 64];
  __shared__ __align__(16) ushort_t Blds[128 * 64];
  const int t = threadIdx.x, wave = t >> 6, lane = t & 63;
  const int l15 = lane & 15, lg = lane >> 4;
  const int m0 = by * 128, n0 = bx * 128;
  const int wr = wave >> 1, wc = wave & 1;
  f32x4 acc[4][4];
#pragma unroll
  for (int i = 0; i < 4; ++i)
#pragma unroll
    for (int j = 0; j < 4; ++j) acc[i][j] = (f32x4){0.f, 0.f, 0.f, 0.f};

  for (int tk = 0; tk < K / 64; ++tk) {
#pragma unroll
    for (int c = 0; c < 4; ++c) {
      int chunk = wave * 4 + c;
      int row = chunk * 8 + (lane >> 3);
      int ss = (lane & 7) ^ (row & 7);
      gld_lds16(A + (size_t)(m0 + row) * K + tk * 64 + ss * 8, (char*)Alds + chunk * 1024);
      gld_lds16(Bt + (size_t)(n0 + row) * K + tk * 64 + ss * 8, (char*)Blds + chunk * 1024);
    }
    __syncthreads();
#pragma unroll
    for (int kk = 0; kk < 2; ++kk) {
      bf16x8 a[4], b[4];
#pragma unroll
      for (int i = 0; i < 4; ++i) {
        int ra = wr * 64 + i * 16 + l15;
        a[i] = *(const bf16x8*)((const char*)Alds + ra * 128 + ((((kk * 4 + lg) << 4)) ^ ((ra & 7) << 4)));
        int rb = wc * 64 + i * 16 + l15;
        b[i] = *(const bf16x8*)((const char*)Blds + rb * 128 + ((((kk * 4 + lg) << 4)) ^ ((rb & 7) << 4)));
      }
#pragma unroll
      for (int mi = 0; mi < 4; ++mi)
#pragma unroll
        for (int ni = 0; ni < 4; ++ni)
          acc[mi][ni] = mfma16(a[mi], b[ni], acc[mi][ni]);
    }
    __syncthreads();
  }
#pragma unroll
  for (int ni = 0; ni < 4; ++ni) {
    int coln = n0 + wc * 64 + ni * 16 + l15;
    float bv = bias[coln];
#pragma unroll
    for (int mi = 0; mi < 4; ++mi) {
#pragma unroll
      for (int r = 0; r < 4; ++r) {
        int rowm = m0 + wr * 64 + mi * 16 + lg * 4 + r;
        float v = (acc[mi][ni][r] + bv) * scale;
        if (OUT_F32)
          ((float*)Cout)[(size_t)rowm * N + coln] = v;
        else
          ((ushort_t*)Cout)[(size_t)rowm * N + coln] = f32_to_bf16(v);
      }
    }
  }
}

// ---------------- fused attention ----------------
// 1D grid 1024, 256 threads (4 waves), wave owns 16 q-rows. XCD-swizzle: 2 heads/XCD.
// qh pre-scaled by TAU*log2(e). pass1: rowsums of exp2(S). pass2: att via LDS f32 tile
// + dwordx4 stores; PV from same tile (cvt to bf16 frags).
__launch_bounds__(256, 4)
__global__ void attn_kernel(const ushort_t* __restrict__ qh, const ushort_t* __restrict__ kh,
                            const ushort_t* __restrict__ vt, float* __restrict__ att,
                            ushort_t* __restrict__ ctx) {
  __shared__ __align__(16) ushort_t Klds[KVB * 64];  // [k-row][d] 128B rows, 8KB
  __shared__ __align__(16) ushort_t Vlds[KVB * 64];  // [x][k]    128B rows, 8KB
  __shared__ __align__(16) float Patt[4][16 * 64];   // per-wave [row][col], 256B rows, swz, 16KB
  const int t = threadIdx.x, wave = t >> 6, lane = t & 63;
  const int l15 = lane & 15, lg = lane >> 4;
  const int bid = blockIdx.x;
  const int xcd = bid & 7, idx = bid >> 3;       // idx 0..127
  const int h = xcd * 2 + (idx >> 6);            // 2 heads per XCD
  const int q0 = (idx & 63) * QBLK;

  char* Pw = (char*)Patt[wave];

  bf16x8 qa[2];
  {
    int row = q0 + wave * 16 + l15;
    const ushort_t* qp = qh + (size_t)row * DIN + h * HD + lg * 8;
    qa[0] = *(const bf16x8*)(qp);
    qa[1] = *(const bf16x8*)(qp + 32);
  }

  // staging geometry (R1-proven): chunk = wave*2+c covers 8 rows x 128B
  const int srow8 = lane >> 3;            // row within chunk
  const int sslot = (lane & 7);

  float rs[4] = {0.f, 0.f, 0.f, 0.f};
  // ---- pass 1: row sums ----
  for (int tk = 0; tk < LKS / KVB; ++tk) {
#pragma unroll
    for (int c = 0; c < 2; ++c) {
      int chunk = wave * 2 + c;
      int row = chunk * 8 + srow8;
      int ss = sslot ^ (row & 7);
      gld_lds16(kh + (size_t)(tk * KVB + row) * DIN + h * HD + ss * 8, (char*)Klds + chunk * 1024);
    }
    __syncthreads();
#pragma unroll
    for (int ct = 0; ct < 4; ++ct) {
      f32x4 acc = (f32x4){0.f, 0.f, 0.f, 0.f};
#pragma unroll
      for (int kk = 0; kk < 2; ++kk) {
        int row = ct * 16 + l15;
        bf16x8 kb = *(const bf16x8*)((const char*)Klds + row * 128 + ((((kk * 4 + lg) << 4)) ^ ((row & 7) << 4)));
        acc = mfma16(qa[kk], kb, acc);
      }
#pragma unroll
      for (int r = 0; r < 4; ++r) rs[r] += exp2_fast(acc[r]);
    }
    __syncthreads();
  }
#pragma unroll
  for (int m = 1; m < 16; m <<= 1) {
#pragma unroll
    for (int r = 0; r < 4; ++r) rs[r] += __shfl_xor(rs[r], m, 64);
  }
  float recip[4];
#pragma unroll
  for (int r = 0; r < 4; ++r) recip[r] = 1.0f / rs[r];

  // ---- pass 2: att write + PV ----
  f32x4 cacc[4];
#pragma unroll
  for (int x = 0; x < 4; ++x) cacc[x] = (f32x4){0.f, 0.f, 0.f, 0.f};
  float* atth = att + ((size_t)h << 24);

  for (int tk = 0; tk < LKS / KVB; ++tk) {
#pragma unroll
    for (int c = 0; c < 2; ++c) {
      int chunk = wave * 2 + c;
      int row = chunk * 8 + srow8;
      int ss = sslot ^ (row & 7);
      gld_lds16(kh + (size_t)(tk * KVB + row) * DIN + h * HD + ss * 8, (char*)Klds + chunk * 1024);
      gld_lds16(vt + ((size_t)h * HD + row) * (size_t)LKS + tk * KVB + ss * 8, (char*)Vlds + chunk * 1024);
    }
    __syncthreads();
    // QK^T -> p -> wave-private LDS f32 tile (16B-slot XOR swizzle by row)
#pragma unroll
    for (int ct = 0; ct < 4; ++ct) {
      f32x4 acc = (f32x4){0.f, 0.f, 0.f, 0.f};
#pragma unroll
      for (int kk = 0; kk < 2; ++kk) {
        int row = ct * 16 + l15;
        bf16x8 kb = *(const bf16x8*)((const char*)Klds + row * 128 + ((((kk * 4 + lg) << 4)) ^ ((row & 7) << 4)));
        acc = mfma16(qa[kk], kb, acc);
      }
#pragma unroll
      for (int r = 0; r < 4; ++r) {
        float p = exp2_fast(acc[r]) * recip[r];
        int R = lg * 4 + r;                 // row in wave tile
        int col = ct * 16 + l15;            // 0..63
        int slot = col >> 2;
        *(float*)(Pw + R * 256 + (((slot ^ R)) << 4) + (col & 3) * 4) = p;
      }
    }
    // att store: 4x dwordx4 per thread; each instr = 16 rows x 64B contiguous
#pragma unroll
    for (int i = 0; i < 4; ++i) {
      int slot = lg + 4 * i;
      f32x4 v = *(const f32x4*)(Pw + l15 * 256 + ((slot ^ l15) << 4));
      int rowq = q0 + wave * 16 + l15;
      *(f32x4*)(atth + (((size_t)rowq) << 12) + tk * KVB + slot * 4) = v;
    }
    // PV A-frags: row l15, k = kk*32 + lg*8 (+0..7) from f32 tile -> bf16
    bf16x8 pa[2];
#pragma unroll
    for (int kk = 0; kk < 2; ++kk) {
      int s0 = kk * 8 + lg * 2;
      f32x4 lo = *(const f32x4*)(Pw + l15 * 256 + ((s0 ^ l15) << 4));
      f32x4 hi = *(const f32x4*)(Pw + l15 * 256 + (((s0 + 1) ^ l15) << 4));
      short8 sp;
#pragma unroll
      for (int j = 0; j < 4; ++j) {
        sp[j] = (short)f32_to_bf16(lo[j]);
        sp[4 + j] = (short)f32_to_bf16(hi[j]);
      }
      pa[kk] = *(bf16x8*)&sp;
    }
#pragma unroll
    for (int x = 0; x < 4; ++x) {
#pragma unroll
      for (int kk = 0; kk < 2; ++kk) {
        int rv = x * 16 + l15;
        bf16x8 vb = *(const bf16x8*)((const char*)Vlds + rv * 128 + ((((kk * 4 + lg) << 4)) ^ ((rv & 7) << 4)));
        cacc[x] = mfma16(pa[kk], vb, cacc[x]);
      }
    }
    __syncthreads();
  }
#pragma unroll
  for (int x = 0; x < 4; ++x) {
#pragma unroll
    for (int r = 0; r < 4; ++r) {
      int rowq = q0 + wave * 16 + lg * 4 + r;
      int col = h * HD + x * 16 + l15;
      ctx[(size_t)rowq * DIN + col] = f32_to_bf16(cacc[x][r]);
    }
  }
}

extern "C" void kernel_launch(void* const* d_in, const int* in_sizes, int n_in,
                              void* d_out, int out_size, void* d_ws, size_t ws_size,
                              hipStream_t stream) {
  const float* q = (const float*)d_in[0];
  const float* k = (const float*)d_in[1];
  const float* v = (const float*)d_in[2];
  const float* Wq = (const float*)d_in[3];
  const float* bq = (const float*)d_in[4];
  const float* Wk = (const float*)d_in[5];
  const float* bk = (const float*)d_in[6];
  const float* Wv = (const float*)d_in[7];
  const float* bv = (const float*)d_in[8];
  const float* Wo = (const float*)d_in[9];
  const float* bo = (const float*)d_in[10];

  float* out = (float*)d_out;
  float* att = out + (size_t)LQS * DIN;

  char* ws = (char*)d_ws;
  ushort_t* qhb = (ushort_t*)(ws + (size_t)0);
  ushort_t* khb = (ushort_t*)(ws + ((size_t)8 << 20));
  ushort_t* vhb = (ushort_t*)(ws + ((size_t)16 << 20));
  ushort_t* vtb = (ushort_t*)(ws + ((size_t)24 << 20));
  ushort_t* ctx = (ushort_t*)(ws + ((size_t)32 << 20));
  ushort_t* qb = (ushort_t*)(ws + ((size_t)40 << 20));
  ushort_t* kb = (ushort_t*)(ws + ((size_t)48 << 20));
  ushort_t* vb = (ushort_t*)(ws + ((size_t)56 << 20));
  ushort_t* Wqt = (ushort_t*)(ws + ((size_t)64 << 20));
  ushort_t* Wkt = (ushort_t*)(ws + ((size_t)66 << 20));
  ushort_t* Wvt = (ushort_t*)(ws + ((size_t)68 << 20));
  ushort_t* Wot = (ushort_t*)(ws + ((size_t)70 << 20));

  Cvt3 c3;
  c3.src[0] = q; c3.src[1] = k; c3.src[2] = v;
  c3.dst[0] = qb; c3.dst[1] = kb; c3.dst[2] = vb;
  cvt_kernel<<<dim3(LQS * DIN / 8 / 256, 3), 256, 0, stream>>>(c3);

  TW4 w4;
  w4.W[0] = Wq; w4.W[1] = Wk; w4.W[2] = Wv; w4.W[3] = Wo;
  w4.Wt[0] = Wqt; w4.Wt[1] = Wkt; w4.Wt[2] = Wvt; w4.Wt[3] = Wot;
  transpose_w<<<dim3(16, 16, 4), 256, 0, stream>>>(w4);

  Batch3 pb;
  pb.A[0] = qb; pb.A[1] = kb; pb.A[2] = vb;
  pb.Bt[0] = Wqt; pb.Bt[1] = Wkt; pb.Bt[2] = Wvt;
  pb.bias[0] = bq; pb.bias[1] = bk; pb.bias[2] = bv;
  pb.C[0] = qhb; pb.C[1] = khb; pb.C[2] = vhb;
  pb.scale[0] = TAU_S * LOG2E; pb.scale[1] = 1.0f; pb.scale[2] = 1.0f;
  gemm_nt<false><<<768, 256, 0, stream>>>(pb);

  transpose_v<<<dim3(64, 16), 256, 0, stream>>>(vhb, vtb);

  attn_kernel<<<1024, 256, 0, stream>>>(qhb, khb, vtb, att, ctx);

  Batch3 ob;
  ob.A[0] = ctx; ob.A[1] = ctx; ob.A[2] = ctx;
  ob.Bt[0] = Wot; ob.Bt[1] = Wot; ob.Bt[2] = Wot;
  ob.bias[0] = bo; ob.bias[1] = bo; ob.bias[2] = bo;
  ob.C[0] = out; ob.C[1] = out; ob.C[2] = out;
  ob.scale[0] = 1.0f; ob.scale[1] = 1.0f; ob.scale[2] = 1.0f;
  gemm_nt<true><<<256, 256, 0, stream>>>(ob);
}